// Round 6
// baseline (94.133 us; speedup 1.0000x reference)
//
#include <hip/hip_runtime.h>
#include <hip/hip_bf16.h>
#include <hip/hip_fp8.h>

#define BDIM 8192
#define DDIM 256
#define NT 64                 // 8192/128 tiles per dim
#define NBLK 2080             // NT*(NT+1)/2 upper-triangle tiles
#define MARGIN1 5.0f
#define MARGIN2 10.0f
#define INV_NPAIRS (1.0f / 33550336.0f)   // 8192*8191/2

typedef __attribute__((ext_vector_type(4))) float f32x4;
typedef __attribute__((ext_vector_type(4))) int   i32x4;
typedef __attribute__((ext_vector_type(8))) int   i32x8;

__device__ inline void gload_lds16(const void* g, void* s) {
    __builtin_amdgcn_global_load_lds(
        (const __attribute__((address_space(1))) void*)g,
        (__attribute__((address_space(3))) void*)s, 16, 0, 0);
}

// One wave per row: fp32 -> fp8 e4m3 (OCP, RNE saturating), sq from the
// DEQUANTIZED values (so d2 = |Q(f_i)-Q(f_j)|^2 is mathematically >= 0),
// pack {sq, label*2+method}.
__global__ __launch_bounds__(256) void prep_kernel(
    const float* __restrict__ F, const int* __restrict__ labels,
    const int* __restrict__ mlabels, unsigned char* __restrict__ Fq,
    float2* __restrict__ meta)
{
    const int row  = blockIdx.x * 4 + (threadIdx.x >> 6);
    const int lane = threadIdx.x & 63;
    f32x4 v = *reinterpret_cast<const f32x4*>(F + (size_t)row * DDIM + lane * 4);
    __hip_fp8_e4m3 q0(v.x), q1(v.y), q2(v.z), q3(v.w);
    unsigned int packed = (unsigned int)q0.__x | ((unsigned int)q1.__x << 8)
                        | ((unsigned int)q2.__x << 16) | ((unsigned int)q3.__x << 24);
    *reinterpret_cast<unsigned int*>(Fq + (size_t)row * DDIM + lane * 4) = packed;
    float f0 = (float)q0, f1 = (float)q1, f2 = (float)q2, f3 = (float)q3;
    float s = f0 * f0 + f1 * f1 + f2 * f2 + f3 * f3;
    #pragma unroll
    for (int off = 32; off > 0; off >>= 1) s += __shfl_xor(s, off, 64);
    if (lane == 0)
        meta[row] = make_float2(s, __int_as_float(labels[row] * 2 + mlabels[row]));
}

#define FT(t) ((t) * (129 - (t)) / 2)   // first linear id of tile-row t

// 128x128 Gram tile per block, 256 threads (4 waves in 2x2, each wave a
// 64x64 subtile = 4x4 of mfma_scale_f32_16x16x128_f8f6f4, unit scales).
// SINGLE-stage full-K staging (one barrier), XOR-swizzled fp8 LDS fed by
// global_load_lds, direct exact epilogue (no guards / second pass).
__global__ __launch_bounds__(256, 2) void pair_loss_kernel(
    const unsigned char* __restrict__ Fq, const float2* __restrict__ meta,
    float* __restrict__ partial)
{
    // linear block id -> upper-triangle (ti, tj)
    const int L = blockIdx.x;
    int ti = (int)((129.0f - sqrtf(16641.0f - 8.0f * (float)L)) * 0.5f);
    while (FT(ti + 1) <= L) ++ti;
    while (FT(ti) > L) --ti;
    const int tj = ti + (L - FT(ti));

    __shared__ __align__(16) unsigned char As[128 * 256];  // full-K tile, 32 KB
    __shared__ __align__(16) unsigned char Bs[128 * 256];
    __shared__ float2 metaS[256];   // [0,128) rows, [128,256) cols
    __shared__ float  red[4];

    const int tid  = threadIdx.x;
    const int lane = tid & 63;
    const int wid  = tid >> 6;
    const int wm   = wid >> 1;      // 0..1
    const int wn   = wid & 1;       // 0..1
    const int quad = lane >> 4;
    const int coll = lane & 15;
    const int rowq = quad * 4;

    const int i0 = ti * 128;
    const int j0 = tj * 128;

    if (tid < 128) metaS[tid] = meta[i0 + tid];
    else           metaS[tid] = meta[j0 + tid - 128];

    // Stage both tiles in one burst: 2048 16B slots each (8/thread each).
    // LDS slot s (16 chunks/row): row = s>>4, sc = s&15, holds global chunk
    // cg = ((sc&7)^(row&7)) | (sc&8)  -> conflict-free DMA write & frag read.
    #pragma unroll
    for (int it = 0; it < 8; ++it) {
        const int slotbase = it * 256 + wid * 64;   // wave-uniform
        const int slot = slotbase + lane;
        const int row  = slot >> 4;                 // 0..127
        const int sc   = slot & 15;
        const int cg   = ((sc & 7) ^ (row & 7)) | (sc & 8);
        gload_lds16(Fq + (size_t)(i0 + row) * DDIM + cg * 16, &As[slotbase * 16]);
        gload_lds16(Fq + (size_t)(j0 + row) * DDIM + cg * 16, &Bs[slotbase * 16]);
    }
    __syncthreads();

    f32x4 acc[4][4];
    #pragma unroll
    for (int a = 0; a < 4; a++)
        #pragma unroll
        for (int b = 0; b < 4; b++)
            acc[a][b] = (f32x4){0.f, 0.f, 0.f, 0.f};

    // K-loop over two K=128 steps; fragments: lane holds m = lane&15,
    // k = quad*32 + [0,32)  -> chunks c = ks*8 + 2*quad, +1.
    #pragma unroll
    for (int ks = 0; ks < 2; ++ks) {
        i32x8 af[4], bf[4];
        #pragma unroll
        for (int t = 0; t < 4; t++) {
            const int ra = wm * 64 + t * 16 + coll;
            const int s0 = (((2 * quad) & 7) ^ (ra & 7)) | (ks * 8);
            const int s1 = (((2 * quad + 1) & 7) ^ (ra & 7)) | (ks * 8);
            i32x4 lo = *reinterpret_cast<const i32x4*>(&As[ra * 256 + s0 * 16]);
            i32x4 hi = *reinterpret_cast<const i32x4*>(&As[ra * 256 + s1 * 16]);
            af[t] = (i32x8){lo.x, lo.y, lo.z, lo.w, hi.x, hi.y, hi.z, hi.w};
        }
        #pragma unroll
        for (int t = 0; t < 4; t++) {
            const int rb = wn * 64 + t * 16 + coll;
            const int s0 = (((2 * quad) & 7) ^ (rb & 7)) | (ks * 8);
            const int s1 = (((2 * quad + 1) & 7) ^ (rb & 7)) | (ks * 8);
            i32x4 lo = *reinterpret_cast<const i32x4*>(&Bs[rb * 256 + s0 * 16]);
            i32x4 hi = *reinterpret_cast<const i32x4*>(&Bs[rb * 256 + s1 * 16]);
            bf[t] = (i32x8){lo.x, lo.y, lo.z, lo.w, hi.x, hi.y, hi.z, hi.w};
        }
        #pragma unroll
        for (int tm = 0; tm < 4; tm++)
            #pragma unroll
            for (int tn = 0; tn < 4; tn++)
                acc[tm][tn] = __builtin_amdgcn_mfma_scale_f32_16x16x128_f8f6f4(
                    af[tm], bf[tn], acc[tm][tn],
                    0 /*A fmt: fp8 e4m3*/, 0 /*B fmt*/,
                    0, 127 /*scale A = 2^0*/, 0, 127 /*scale B = 2^0*/);
    }

    // --- Direct exact epilogue. C/D layout: col = lane&15, row = quad*4+reg.
    // term = same_label ? dist : relu(margin - dist); margin = (same_method?5:10).
    const bool offdiag = (ti != tj);
    float sj[4]; int cj[4];
    #pragma unroll
    for (int tn = 0; tn < 4; tn++) {
        float2 mm = metaS[128 + wn * 64 + tn * 16 + coll];
        sj[tn] = mm.x; cj[tn] = __float_as_int(mm.y);
    }

    float lsum = 0.0f;
    #pragma unroll
    for (int tm = 0; tm < 4; tm++) {
        #pragma unroll
        for (int r = 0; r < 4; r++) {
            const int il = wm * 64 + tm * 16 + rowq + r;
            float2 mr = metaS[il];
            const float si = mr.x;
            const int   ci = __float_as_int(mr.y);
            #pragma unroll
            for (int tn = 0; tn < 4; tn++) {
                const int jl = wn * 64 + tn * 16 + coll;
                float d2   = fmaxf(fmaf(acc[tm][tn][r], -2.0f, si + sj[tn]), 0.0f);
                float dist = __builtin_amdgcn_sqrtf(d2);
                int   x    = ci ^ cj[tn];
                float marg = (x & 1) ? MARGIN2 : MARGIN1;
                float term = (((unsigned)x) < 2u) ? dist : fmaxf(marg - dist, 0.0f);
                bool  w    = offdiag | (il < jl);
                lsum += w ? term : 0.0f;
            }
        }
    }

    #pragma unroll
    for (int off = 32; off > 0; off >>= 1) lsum += __shfl_xor(lsum, off, 64);
    if (lane == 0) red[wid] = lsum;
    __syncthreads();
    if (tid == 0) partial[L] = red[0] + red[1] + red[2] + red[3];
}

__global__ __launch_bounds__(256) void reduce_kernel(
    const float* __restrict__ partial, float* __restrict__ out)
{
    __shared__ float red[4];
    float s = 0.0f;
    for (int i = threadIdx.x; i < NBLK; i += 256) s += partial[i];
    #pragma unroll
    for (int off = 32; off > 0; off >>= 1) s += __shfl_xor(s, off, 64);
    const int lane = threadIdx.x & 63, wid = threadIdx.x >> 6;
    if (lane == 0) red[wid] = s;
    __syncthreads();
    if (threadIdx.x == 0)
        out[0] = (red[0] + red[1] + red[2] + red[3]) * INV_NPAIRS;
}

extern "C" void kernel_launch(void* const* d_in, const int* in_sizes, int n_in,
                              void* d_out, int out_size, void* d_ws, size_t ws_size,
                              hipStream_t stream) {
    const float* F       = (const float*)d_in[0];
    const int*   labels  = (const int*)d_in[1];
    const int*   mlabels = (const int*)d_in[2];
    float*       out     = (float*)d_out;

    unsigned char* Fq      = (unsigned char*)d_ws;                         // 2 MiB
    float2*        meta    = (float2*)((char*)d_ws + (size_t)BDIM * DDIM); // 64 KiB
    float*         partial = (float*)((char*)meta + (size_t)BDIM * sizeof(float2));

    prep_kernel<<<BDIM / 4, 256, 0, stream>>>(F, labels, mlabels, Fq, meta);
    pair_loss_kernel<<<NBLK, 256, 0, stream>>>(Fq, meta, partial);
    reduce_kernel<<<1, 256, 0, stream>>>(partial, out);
}